// Round 2
// baseline (19936.781 us; speedup 1.0000x reference)
//
#include <hip/hip_runtime.h>
#include <hip/hip_bf16.h>

// =====================================================================
// PlantLSTM R2: weight-RESIDENT design.
//  - 16 groups x 16 WGs = 256 WGs (1 per CU, forced by 139KB LDS).
//  - Group owns 16 batch elems; WG j owns 16 hidden units (64 gate rows).
//  - All LSTM weights live in LDS for the whole kernel (no per-step L2
//    weight stream -> beats the ~150GB/s-per-CU streaming floor).
//  - Per step: L0 gates -> cell -> h0 all-gather (512B/WG, device-scope
//    atomics + flag) -> L1 gates -> cell -> h1 all-gather -> FC head
//    (register-resident weights, own batch) -> pv scatter.
//  - Flags use exact-match (==t+1) polling: stale values from previous
//    graph replays (==512 or 0xAA..) can never match, producers reset
//    their own slots at start; 2-deep parity ring is race-free because
//    a producer reaching step t+2 implies all consumers finished t.
//  - Group WGs share an XCD via bid%8 mapping (perf only, not correctness).
// =====================================================================

#define TSTEPS 512
#define NIN    32

typedef _Float16 h2 __attribute__((ext_vector_type(2)));
#if __has_builtin(__builtin_amdgcn_fdot2)
#define FDOT2(a, b, c) __builtin_amdgcn_fdot2((a), (b), (c), false)
#else
#define FDOT2(a, b, c) ((c) + (float)(a).x * (float)(b).x + (float)(a).y * (float)(b).y)
#endif

__device__ __forceinline__ float sigm(float x) { return 1.0f / (1.0f + __expf(-x)); }
__device__ __forceinline__ float tanhf_(float x) {
    float e = __expf(2.0f * x);
    return 1.0f - 2.0f / (e + 1.0f);
}

// ---- workspace layout (bytes) ----
#define W0T_OFF 0u            // [16 j][64 rl][296 f16]  = 606,208
#define W1T_OFF 606208u       // [16 j][64 rl][512 f16]  = 1,048,576
#define F1T_OFF 1654784u      // [128 row][4 ks][64 f16] = 65,536
#define F2T_OFF 1720320u      // [8 jo][128 f16]         = 2,048
#define HX0_OFF 2097152u      // [16 g][2 par][16 j][512B]
#define HX1_OFF 2359296u
#define PVX_OFF 2621440u      // [16 g][2 par][16 j][16B]
#define FLG_OFF 2629632u      // [16 g][16 j][3 kind][64B]
#define WS_NEED 2678784u

// LDS row strides (bytes) - chosen for gcd(stride/4, 32) <= 4 on b128 reads
#define W0S 592
#define W1S 1040
#define X0S 608
#define X1S 1040

// ------------------------- prep kernels -------------------------
__global__ void prep_w(const float* __restrict__ Wih0, const float* __restrict__ Whh0,
                       const float* __restrict__ Wih1, const float* __restrict__ Whh1,
                       char* __restrict__ ws) {
    int gid = blockIdx.x * 256 + threadIdx.x;
    _Float16* w0 = (_Float16*)(ws + W0T_OFF);
    _Float16* w1 = (_Float16*)(ws + W1T_OFF);
    if (gid < 16 * 64 * 296) {
        int k = gid % 296;
        int rest = gid / 296;
        int rl = rest & 63, j = rest >> 6;
        int row = (rl >> 4) * 256 + j * 16 + (rl & 15);
        float v;
        if (k < 32) v = Wih0[row * 72 + k];                 // x part
        else if (k < 288) v = Whh0[row * 256 + (k - 32)];   // h0 part
        else v = Wih0[row * 72 + 32 + (k - 288)];           // pv part (cols 32..39)
        w0[(j * 64 + rl) * 296 + k] = (_Float16)v;
    } else {
        int gid2 = gid - 16 * 64 * 296;
        if (gid2 < 16 * 64 * 512) {
            int k = gid2 & 511;
            int rest = gid2 >> 9;
            int rl = rest & 63, j = rest >> 6;
            int row = (rl >> 4) * 256 + j * 16 + (rl & 15);
            float v = (k < 256) ? Wih1[row * 256 + k] : Whh1[row * 256 + (k - 256)];
            w1[(j * 64 + rl) * 512 + k] = (_Float16)v;
        }
    }
}

__global__ void prep_fc(const float* __restrict__ fc1w, const float* __restrict__ fc2w,
                        char* __restrict__ ws) {
    int gid = blockIdx.x * 256 + threadIdx.x;
    _Float16* f1 = (_Float16*)(ws + F1T_OFF);
    _Float16* f2 = (_Float16*)(ws + F2T_OFF);
    if (gid < 32768) {  // [row][ks][64]
        int e = gid & 63, ks = (gid >> 6) & 3, r = gid >> 8;
        f1[gid] = (_Float16)fc1w[r * 256 + ks * 64 + e];
    } else if (gid < 32768 + 1024) {
        int i = gid - 32768;
        f2[i] = (_Float16)fc2w[i];
    }
}

// ------------------------- main kernel -------------------------
__global__ __launch_bounds__(512) void lstm_main(
    const float* __restrict__ x_cv, const float* __restrict__ pv_init,
    const int* __restrict__ scen, const float* __restrict__ emb_table,
    const float* __restrict__ Wih0, const float* __restrict__ b_ih0,
    const float* __restrict__ b_hh0, const float* __restrict__ b_ih1,
    const float* __restrict__ b_hh1, const float* __restrict__ fc1_b,
    const float* __restrict__ fc2_b, char* __restrict__ ws,
    float* __restrict__ out) {
    struct __align__(16) SM {
        char w0[64 * W0S];       // 37888
        char w1[64 * W1S];       // 66560
        char xt0[16 * X0S];      // 9728  [b][296 f16 + pad]: x|h0|pv
        char xt1[16 * X1S];      // 16640 [b][512 f16 + pad]: h0|h1
        float gates[16][64];     // 4096
        float biasE[16][64];     // 4096  (L0 bias + emb folded, per batch)
        float bias1[64];         // 256
        _Float16 htmp[16][16];   // 512
        float embs[16][32];      // 2048
        float fc1o[128];         // 512
        int scen_l[16];          // 64
    };
    __shared__ SM sm;

    const int tid = threadIdx.x;
    const int lane = tid & 63;
    const int wv = tid >> 6;
    const int bid = blockIdx.x;
    // group-of-16 shares XCD (bid%8) for L2-local exchange (perf heuristic)
    const int g = (bid & 7) * 2 + ((bid >> 3) & 1);
    const int j = bid >> 4;
    const int B0 = g * 16;

    const char* w0g = ws + W0T_OFF + (unsigned)j * (64u * 296u * 2u);
    const char* w1g = ws + W1T_OFF + (unsigned)j * (64u * 512u * 2u);
    unsigned long long* hx0 = (unsigned long long*)(ws + HX0_OFF) + (unsigned)g * 2u * 16u * 64u;
    unsigned long long* hx1 = (unsigned long long*)(ws + HX1_OFF) + (unsigned)g * 2u * 16u * 64u;
    unsigned long long* pvx = (unsigned long long*)(ws + PVX_OFF) + (unsigned)g * 2u * 16u * 2u;
    unsigned int* flg = (unsigned int*)(ws + FLG_OFF) + (unsigned)g * 16u * 3u * 16u;

    // ---- phase 0: scenario ids + reset OWN flags ----
    if (tid < 16) sm.scen_l[tid] = scen[B0 + tid];
    if (tid == 0) {
        __hip_atomic_store(&flg[(j * 3 + 0) * 16], 0u, __ATOMIC_RELAXED, __HIP_MEMORY_SCOPE_AGENT);
        __hip_atomic_store(&flg[(j * 3 + 1) * 16], 0u, __ATOMIC_RELAXED, __HIP_MEMORY_SCOPE_AGENT);
        __hip_atomic_store(&flg[(j * 3 + 2) * 16], 0u, __ATOMIC_RELAXED, __HIP_MEMORY_SCOPE_AGENT);
    }
    __syncthreads();

    // ---- phase 1: embs, zero xt, load weights into LDS ----
    {
        int b = tid >> 5, e = tid & 31;
        sm.embs[b][e] = emb_table[sm.scen_l[b] * 32 + e];
    }
    for (int idx = tid; idx < (16 * X0S) / 8; idx += 512) ((unsigned long long*)sm.xt0)[idx] = 0ull;
    for (int idx = tid; idx < (16 * X1S) / 8; idx += 512) ((unsigned long long*)sm.xt1)[idx] = 0ull;
    for (int idx = tid; idx < 64 * 37; idx += 512) {
        int r = idx / 37, c = idx - r * 37;
        *(float4*)(&sm.w0[r * W0S + c * 16]) = *(const float4*)(w0g + r * 592 + c * 16);
    }
    for (int idx = tid; idx < 64 * 64; idx += 512) {
        int r = idx >> 6, c = idx & 63;
        *(float4*)(&sm.w1[r * W1S + c * 16]) = *(const float4*)(w1g + r * 1024 + c * 16);
    }
    __syncthreads();

    // ---- phase 2: biases (emb folded into L0 bias), FC register weights ----
    for (int idx = tid; idx < 1024; idx += 512) {
        int b = idx >> 6, rl = idx & 63;
        int row = (rl >> 4) * 256 + j * 16 + (rl & 15);
        float s = b_ih0[row] + b_hh0[row];
        for (int e = 0; e < 32; ++e) s += sm.embs[b][e] * Wih0[row * 72 + 40 + e];
        sm.biasE[b][rl] = s;
    }
    if (tid < 64) {
        int row = (tid >> 4) * 256 + j * 16 + (tid & 15);
        sm.bias1[tid] = b_ih1[row] + b_hh1[row];
    }
    float4 f1w[8];
    {
        const char* f1g = ws + F1T_OFF + (unsigned)tid * 128u;
#pragma unroll
        for (int q = 0; q < 8; ++q) f1w[q] = *(const float4*)(f1g + q * 16);
    }
    float f2w[16];
    if (wv == 0) {
        int jo = lane >> 3, ks2 = lane & 7;
        const _Float16* f2g = (const _Float16*)(ws + F2T_OFF) + jo * 128 + ks2 * 16;
#pragma unroll
        for (int q = 0; q < 16; ++q) f2w[q] = (float)f2g[q];
    }
    const float fc2b_r = (wv == 0) ? fc2_b[lane >> 3] : 0.0f;
    const float fc1b_r = fc1_b[tid >> 2];
    float c0 = 0.0f, c1 = 0.0f;
    __syncthreads();

    // ==================== time loop ====================
    for (int t = 0; t < TSTEPS; ++t) {
        const int par = t & 1;

        // ---- stage: x(t), pv(t-1), gates <- biasE ----
        {
            int b = tid >> 5, k = tid & 31;
            float xv = x_cv[((B0 + b) * TSTEPS + t) * NIN + k];
            *(_Float16*)(&sm.xt0[b * X0S + k * 2]) = (_Float16)xv;
        }
        for (int idx = tid; idx < 1024; idx += 512) {
            int b = idx >> 6, rl = idx & 63;
            sm.gates[b][rl] = sm.biasE[b][rl];
        }
        if (wv == 0 && lane < 16) {
            if (t == 0) {
                const float* pp = pv_init + (B0 + lane) * 8;
#pragma unroll
                for (int q = 0; q < 8; ++q)
                    *(_Float16*)(&sm.xt0[lane * X0S + (288 + q) * 2]) = (_Float16)pp[q];
            } else {
                while (__hip_atomic_load(&flg[(lane * 3 + 2) * 16], __ATOMIC_ACQUIRE,
                                         __HIP_MEMORY_SCOPE_AGENT) != (unsigned)t) {}
                int pp = (t - 1) & 1;
                unsigned long long v0 = __hip_atomic_load(&pvx[(pp * 16 + lane) * 2 + 0],
                                                          __ATOMIC_RELAXED, __HIP_MEMORY_SCOPE_AGENT);
                unsigned long long v1 = __hip_atomic_load(&pvx[(pp * 16 + lane) * 2 + 1],
                                                          __ATOMIC_RELAXED, __HIP_MEMORY_SCOPE_AGENT);
                *(unsigned long long*)(&sm.xt0[lane * X0S + 576]) = v0;
                *(unsigned long long*)(&sm.xt0[lane * X0S + 584]) = v1;
            }
        }
        __syncthreads();  // B1

        // ---- L0 gates: lane=row, waves split 37 K-chunks ----
        {
            float acc[16];
#pragma unroll
            for (int b = 0; b < 16; ++b) acc[b] = 0.0f;
            for (int c = wv; c < 37; c += 8) {
                float4 w = *(const float4*)(&sm.w0[lane * W0S + c * 16]);
                h2 w0_ = __builtin_bit_cast(h2, w.x), w1_ = __builtin_bit_cast(h2, w.y);
                h2 w2_ = __builtin_bit_cast(h2, w.z), w3_ = __builtin_bit_cast(h2, w.w);
#pragma unroll
                for (int b = 0; b < 16; ++b) {
                    float4 xv = *(const float4*)(&sm.xt0[b * X0S + c * 16]);
                    acc[b] = FDOT2(w0_, __builtin_bit_cast(h2, xv.x), acc[b]);
                    acc[b] = FDOT2(w1_, __builtin_bit_cast(h2, xv.y), acc[b]);
                    acc[b] = FDOT2(w2_, __builtin_bit_cast(h2, xv.z), acc[b]);
                    acc[b] = FDOT2(w3_, __builtin_bit_cast(h2, xv.w), acc[b]);
                }
            }
#pragma unroll
            for (int b = 0; b < 16; ++b) atomicAdd(&sm.gates[b][lane], acc[b]);
        }
        __syncthreads();  // B2

        // ---- cell 0 ----
        if (tid < 256) {
            int ui = tid & 15, b = tid >> 4;
            float gi = sm.gates[b][ui], gf = sm.gates[b][16 + ui];
            float gc = sm.gates[b][32 + ui], go = sm.gates[b][48 + ui];
            c0 = sigm(gf) * c0 + sigm(gi) * tanhf_(gc);
            sm.htmp[b][ui] = (_Float16)(sigm(go) * tanhf_(c0));
        }
        __syncthreads();  // B3

        // ---- post h0 slice + poll all 16 ----
        if (wv == 0) {
            unsigned long long v = *(const unsigned long long*)(&sm.htmp[lane >> 2][(lane & 3) * 4]);
            __hip_atomic_store(&hx0[(par * 16 + j) * 64 + lane], v, __ATOMIC_RELAXED,
                               __HIP_MEMORY_SCOPE_AGENT);
            if (lane == 0)
                __hip_atomic_store(&flg[(j * 3 + 0) * 16], (unsigned)(t + 1), __ATOMIC_RELEASE,
                                   __HIP_MEMORY_SCOPE_AGENT);
            if (lane < 16)
                while (__hip_atomic_load(&flg[(lane * 3 + 0) * 16], __ATOMIC_ACQUIRE,
                                         __HIP_MEMORY_SCOPE_AGENT) != (unsigned)(t + 1)) {}
        }
        __syncthreads();  // B4

        // ---- gather h0 -> xt1[0:256] and xt0[h0 part]; gates <- bias1 ----
        for (int idx = tid; idx < 1024; idx += 512) {
            int jj = idx >> 6, l = idx & 63;
            unsigned long long v = __hip_atomic_load(&hx0[(par * 16 + jj) * 64 + l],
                                                     __ATOMIC_RELAXED, __HIP_MEMORY_SCOPE_AGENT);
            int b = l >> 2, u = jj * 16 + (l & 3) * 4;
            *(unsigned long long*)(&sm.xt1[b * X1S + u * 2]) = v;
            *(unsigned long long*)(&sm.xt0[b * X0S + (32 + u) * 2]) = v;
        }
        for (int idx = tid; idx < 1024; idx += 512) {
            int b = idx >> 6, rl = idx & 63;
            sm.gates[b][rl] = sm.bias1[rl];
        }
        __syncthreads();  // B5

        // ---- L1 gates: 64 K-chunks ----
        {
            float acc[16];
#pragma unroll
            for (int b = 0; b < 16; ++b) acc[b] = 0.0f;
            for (int c = wv; c < 64; c += 8) {
                float4 w = *(const float4*)(&sm.w1[lane * W1S + c * 16]);
                h2 w0_ = __builtin_bit_cast(h2, w.x), w1_ = __builtin_bit_cast(h2, w.y);
                h2 w2_ = __builtin_bit_cast(h2, w.z), w3_ = __builtin_bit_cast(h2, w.w);
#pragma unroll
                for (int b = 0; b < 16; ++b) {
                    float4 xv = *(const float4*)(&sm.xt1[b * X1S + c * 16]);
                    acc[b] = FDOT2(w0_, __builtin_bit_cast(h2, xv.x), acc[b]);
                    acc[b] = FDOT2(w1_, __builtin_bit_cast(h2, xv.y), acc[b]);
                    acc[b] = FDOT2(w2_, __builtin_bit_cast(h2, xv.z), acc[b]);
                    acc[b] = FDOT2(w3_, __builtin_bit_cast(h2, xv.w), acc[b]);
                }
            }
#pragma unroll
            for (int b = 0; b < 16; ++b) atomicAdd(&sm.gates[b][lane], acc[b]);
        }
        __syncthreads();  // B6

        // ---- cell 1 ----
        if (tid < 256) {
            int ui = tid & 15, b = tid >> 4;
            float gi = sm.gates[b][ui], gf = sm.gates[b][16 + ui];
            float gc = sm.gates[b][32 + ui], go = sm.gates[b][48 + ui];
            c1 = sigm(gf) * c1 + sigm(gi) * tanhf_(gc);
            sm.htmp[b][ui] = (_Float16)(sigm(go) * tanhf_(c1));
        }
        __syncthreads();  // B7

        // ---- post h1 slice + poll ----
        if (wv == 0) {
            unsigned long long v = *(const unsigned long long*)(&sm.htmp[lane >> 2][(lane & 3) * 4]);
            __hip_atomic_store(&hx1[(par * 16 + j) * 64 + lane], v, __ATOMIC_RELAXED,
                               __HIP_MEMORY_SCOPE_AGENT);
            if (lane == 0)
                __hip_atomic_store(&flg[(j * 3 + 1) * 16], (unsigned)(t + 1), __ATOMIC_RELEASE,
                                   __HIP_MEMORY_SCOPE_AGENT);
            if (lane < 16)
                while (__hip_atomic_load(&flg[(lane * 3 + 1) * 16], __ATOMIC_ACQUIRE,
                                         __HIP_MEMORY_SCOPE_AGENT) != (unsigned)(t + 1)) {}
        }
        __syncthreads();  // B8

        // ---- gather h1 -> xt1[256:512] ----
        for (int idx = tid; idx < 1024; idx += 512) {
            int jj = idx >> 6, l = idx & 63;
            unsigned long long v = __hip_atomic_load(&hx1[(par * 16 + jj) * 64 + l],
                                                     __ATOMIC_RELAXED, __HIP_MEMORY_SCOPE_AGENT);
            int b = l >> 2, u = jj * 16 + (l & 3) * 4;
            *(unsigned long long*)(&sm.xt1[b * X1S + (256 + u) * 2]) = v;
        }
        __syncthreads();  // B9

        // ---- FC1 for OWN batch j (reg weights), 4-lane K-split ----
        {
            int row = tid >> 2, ks = tid & 3;
            float a = 0.0f;
#pragma unroll
            for (int q = 0; q < 8; ++q) {
                float4 xv = *(const float4*)(&sm.xt1[j * X1S + (256 + ks * 64 + q * 8) * 2]);
                a = FDOT2(__builtin_bit_cast(h2, f1w[q].x), __builtin_bit_cast(h2, xv.x), a);
                a = FDOT2(__builtin_bit_cast(h2, f1w[q].y), __builtin_bit_cast(h2, xv.y), a);
                a = FDOT2(__builtin_bit_cast(h2, f1w[q].z), __builtin_bit_cast(h2, xv.z), a);
                a = FDOT2(__builtin_bit_cast(h2, f1w[q].w), __builtin_bit_cast(h2, xv.w), a);
            }
            a += __shfl_xor(a, 1);
            a += __shfl_xor(a, 2);
            if (ks == 0) sm.fc1o[row] = fmaxf(a + fc1b_r, 0.0f);
        }
        __syncthreads();  // B10

        // ---- FC2 (wave 0) + out + pv post ----
        if (wv == 0) {
            int jo = lane >> 3, ks2 = lane & 7;
            float a = 0.0f;
#pragma unroll
            for (int q = 0; q < 4; ++q) {
                float4 xv = *(const float4*)(&sm.fc1o[ks2 * 16 + q * 4]);
                a += f2w[q * 4 + 0] * xv.x + f2w[q * 4 + 1] * xv.y +
                     f2w[q * 4 + 2] * xv.z + f2w[q * 4 + 3] * xv.w;
            }
            a += __shfl_xor(a, 1);
            a += __shfl_xor(a, 2);
            a += __shfl_xor(a, 4);
            float av = a + fc2b_r;
            if (ks2 == 0) out[((B0 + j) * TSTEPS + t) * 8 + jo] = av;
            float p0 = __shfl(av, 0), p1 = __shfl(av, 8), p2 = __shfl(av, 16), p3 = __shfl(av, 24);
            float p4 = __shfl(av, 32), p5 = __shfl(av, 40), p6 = __shfl(av, 48), p7 = __shfl(av, 56);
            if (lane == 0) {
                h2 q0, q1, q2, q3;
                q0.x = (_Float16)p0; q0.y = (_Float16)p1;
                q1.x = (_Float16)p2; q1.y = (_Float16)p3;
                q2.x = (_Float16)p4; q2.y = (_Float16)p5;
                q3.x = (_Float16)p6; q3.y = (_Float16)p7;
                unsigned long long v0 = ((unsigned long long)__builtin_bit_cast(unsigned, q1) << 32) |
                                        __builtin_bit_cast(unsigned, q0);
                unsigned long long v1 = ((unsigned long long)__builtin_bit_cast(unsigned, q3) << 32) |
                                        __builtin_bit_cast(unsigned, q2);
                __hip_atomic_store(&pvx[(par * 16 + j) * 2 + 0], v0, __ATOMIC_RELAXED,
                                   __HIP_MEMORY_SCOPE_AGENT);
                __hip_atomic_store(&pvx[(par * 16 + j) * 2 + 1], v1, __ATOMIC_RELAXED,
                                   __HIP_MEMORY_SCOPE_AGENT);
                __hip_atomic_store(&flg[(j * 3 + 2) * 16], (unsigned)(t + 1), __ATOMIC_RELEASE,
                                   __HIP_MEMORY_SCOPE_AGENT);
            }
        }
        // next iteration's B1 separates stage writes from wave0's tail work
    }
}

// ------------------------- launch -------------------------
extern "C" void kernel_launch(void* const* d_in, const int* in_sizes, int n_in,
                              void* d_out, int out_size, void* d_ws, size_t ws_size,
                              hipStream_t stream) {
    if (ws_size < WS_NEED) return;  // loud failure: output stays poisoned

    const float* x_cv = (const float*)d_in[0];
    const float* pv_init = (const float*)d_in[1];
    const int* scen = (const int*)d_in[2];
    const float* embt = (const float*)d_in[3];
    const float* Wih0 = (const float*)d_in[4];
    const float* Whh0 = (const float*)d_in[5];
    const float* bih0 = (const float*)d_in[6];
    const float* bhh0 = (const float*)d_in[7];
    const float* Wih1 = (const float*)d_in[8];
    const float* Whh1 = (const float*)d_in[9];
    const float* bih1 = (const float*)d_in[10];
    const float* bhh1 = (const float*)d_in[11];
    const float* fc1w = (const float*)d_in[12];
    const float* fc1b = (const float*)d_in[13];
    const float* fc2w = (const float*)d_in[14];
    const float* fc2b = (const float*)d_in[15];

    char* ws = (char*)d_ws;

    prep_w<<<3232, 256, 0, stream>>>(Wih0, Whh0, Wih1, Whh1, ws);
    prep_fc<<<132, 256, 0, stream>>>(fc1w, fc2w, ws);

    lstm_main<<<256, 512, 0, stream>>>(x_cv, pv_init, scen, embt, Wih0, bih0, bhh0,
                                       bih1, bhh1, fc1b, fc2b, ws, (float*)d_out);
}